// Round 5
// baseline (451.294 us; speedup 1.0000x reference)
//
#include <hip/hip_runtime.h>
#include <stdint.h>
#include <math.h>

#define GROUP 128
#define ZP 8
#define BM 128
#define BN 128
#define BK 32

typedef short short8 __attribute__((ext_vector_type(8)));   // 8 x bf16 bits
typedef float floatx4 __attribute__((ext_vector_type(4)));

typedef __attribute__((address_space(3))) void lds_void;
typedef const __attribute__((address_space(1))) void gbl_void;
#define GLOAD_LDS16(g, l) \
  __builtin_amdgcn_global_load_lds((gbl_void*)(g), (lds_void*)(l), 16, 0, 0)

__device__ __forceinline__ ushort f2bf(float f) {  // round-to-nearest-even
    union { float f; uint32_t i; } v; v.f = f;
    uint32_t r = v.i + 0x7FFF + ((v.i >> 16) & 1);
    return (ushort)(r >> 16);
}

// ---------------------------------------------------------------------------
// x fp32 [M*K] -> bf16 [M*K]. Grid-stride, 8 elems/thread/iter.
// ---------------------------------------------------------------------------
__global__ __launch_bounds__(256) void conv_x_kernel(
    const float* __restrict__ x, ushort* __restrict__ xb, size_t total8)
{
    const size_t stride = (size_t)gridDim.x * 256;
    for (size_t id = (size_t)blockIdx.x * 256 + threadIdx.x; id < total8; id += stride) {
        const float4 a = *reinterpret_cast<const float4*>(x + id * 8);
        const float4 b = *reinterpret_cast<const float4*>(x + id * 8 + 4);
        ushort o[8] __attribute__((aligned(16)));
        o[0] = f2bf(a.x); o[1] = f2bf(a.y); o[2] = f2bf(a.z); o[3] = f2bf(a.w);
        o[4] = f2bf(b.x); o[5] = f2bf(b.y); o[6] = f2bf(b.z); o[7] = f2bf(b.w);
        *reinterpret_cast<uint4*>(xb + id * 8) = *reinterpret_cast<const uint4*>(o);
    }
}

// ---------------------------------------------------------------------------
// Dequant + transpose: wt[n][k] = bf16((q[k][n] - 8) * scale_f32[k/128][n])
// 64x64 tiles, coalesced int4 read, LDS transpose, coalesced 8B write.
// ---------------------------------------------------------------------------
__global__ __launch_bounds__(256) void dequant_t_kernel(
    const int* __restrict__ q, const float* __restrict__ scale,
    ushort* __restrict__ wt, int K, int N)
{
    __shared__ ushort T[64 * 68];     // stride 68: 8B-aligned rows, low conflict
    const int t  = threadIdx.x;
    const int k0 = blockIdx.x * 64;
    const int n0 = blockIdx.y * 64;
    const int g  = k0 / GROUP;        // 64-row tile lies within one 128-group
    const int c  = (t & 15) * 4;      // n offset within tile
    const int r0 = (t >> 4);          // base k row within tile

    const float4 s = *reinterpret_cast<const float4*>(&scale[(size_t)g * N + n0 + c]);

#pragma unroll
    for (int j = 0; j < 4; ++j) {
        const int r = r0 + j * 16;
        const int4 qv = *reinterpret_cast<const int4*>(&q[(size_t)(k0 + r) * N + n0 + c]);
        T[(c + 0) * 68 + r] = f2bf((float)(qv.x - ZP) * s.x);
        T[(c + 1) * 68 + r] = f2bf((float)(qv.y - ZP) * s.y);
        T[(c + 2) * 68 + r] = f2bf((float)(qv.z - ZP) * s.z);
        T[(c + 3) * 68 + r] = f2bf((float)(qv.w - ZP) * s.w);
    }
    __syncthreads();
#pragma unroll
    for (int j = 0; j < 4; ++j) {
        const int nn = r0 + j * 16;   // n within tile
        const int kk = c;             // k within tile
        const uint2 v = *reinterpret_cast<const uint2*>(&T[nn * 68 + kk]);
        *reinterpret_cast<uint2*>(&wt[(size_t)(n0 + nn) * K + k0 + kk]) = v;
    }
}

// ---------------------------------------------------------------------------
// GEMM: A bf16 [M][K] (= converted x)  x  Wt bf16 [N][K]  ->  out fp32 [M][N]
// 128x128 tile, BK=32, 4 waves (2x2), 4x4 16x16x32 bf16 fragments per wave.
// ACONV=true: A staged from fp32 x with in-flight conversion (small-ws path).
// ---------------------------------------------------------------------------
template <bool ACONV>
__global__ __launch_bounds__(256) void gemm_kernel(
    const ushort* __restrict__ Ab, const float* __restrict__ Af,
    const ushort* __restrict__ Wt, float* __restrict__ out,
    int M, int N, int K)
{
    __shared__ ushort As[BM * BK];
    __shared__ ushort Bs[BN * BK];

    const int bid = blockIdx.x;
    const int nwg = gridDim.x;
    int wg = bid;
    if ((nwg & 7) == 0) {             // bijective XCD swizzle
        const int cpx = nwg >> 3;
        wg = (bid & 7) * cpx + (bid >> 3);
    }
    const int ntn = N / BN;
    const int m0 = (wg / ntn) * BM;
    const int n0 = (wg % ntn) * BN;

    const int t    = threadIdx.x;
    const int lane = t & 63;
    const int w    = t >> 6;
    const int wm   = w >> 1;          // 2x2 wave grid
    const int wn   = w & 1;

    floatx4 acc[4][4];
#pragma unroll
    for (int i = 0; i < 4; ++i)
#pragma unroll
        for (int j = 0; j < 4; ++j) acc[i][j] = floatx4{0.f, 0.f, 0.f, 0.f};

    // flat staging offsets: f = i*4096 + t*16 bytes over the 8KB bf16 tile
    int frow[2], fcol[2];
#pragma unroll
    for (int i = 0; i < 2; ++i) {
        const int f = i * 4096 + t * 16;
        frow[i] = f >> 6;             // tile row (64B = 32 bf16 per row)
        fcol[i] = f & 63;             // byte offset within row
    }

    const int lrow = lane & 15;
    const int lk   = (lane >> 4) * 8;

    for (int kt = 0; kt < K; kt += BK) {
        if constexpr (!ACONV) {
#pragma unroll
            for (int i = 0; i < 2; ++i) {
                const char* ga = (const char*)Ab +
                    ((size_t)(m0 + frow[i]) * K + kt) * 2 + fcol[i];
                GLOAD_LDS16(ga, (char*)As + i * 4096 + w * 1024);
            }
        }
#pragma unroll
        for (int i = 0; i < 2; ++i) {
            const char* gb = (const char*)Wt +
                ((size_t)(n0 + frow[i]) * K + kt) * 2 + fcol[i];
            GLOAD_LDS16(gb, (char*)Bs + i * 4096 + w * 1024);
        }
        if constexpr (ACONV) {
            // thread t: row = t>>1, cols (t&1)*16 .. +15 of the fp32 A tile
            const int r  = t >> 1;
            const int c0 = (t & 1) * 16;
            const float* src = Af + (size_t)(m0 + r) * K + kt + c0;
            ushort o[16] __attribute__((aligned(16)));
#pragma unroll
            for (int j = 0; j < 16; ++j) o[j] = f2bf(src[j]);
            __syncthreads();          // prev tile's ds_reads done before overwrite
            *reinterpret_cast<uint4*>(&As[r * BK + c0]) =
                *reinterpret_cast<const uint4*>(&o[0]);
            *reinterpret_cast<uint4*>(&As[r * BK + c0 + 8]) =
                *reinterpret_cast<const uint4*>(&o[8]);
        }
        __syncthreads();

        short8 af[4], bf[4];
#pragma unroll
        for (int i = 0; i < 4; ++i) {
            af[i] = *reinterpret_cast<const short8*>(&As[(wm * 64 + i * 16 + lrow) * BK + lk]);
            bf[i] = *reinterpret_cast<const short8*>(&Bs[(wn * 64 + i * 16 + lrow) * BK + lk]);
        }
#pragma unroll
        for (int i = 0; i < 4; ++i)
#pragma unroll
            for (int j = 0; j < 4; ++j)
                acc[i][j] = __builtin_amdgcn_mfma_f32_16x16x32_bf16(af[i], bf[j], acc[i][j], 0, 0, 0);
        __syncthreads();
    }

    // epilogue (fp32 out): D col = lane&15, row = 4*(lane>>4)+reg
    const int orow0 = m0 + wm * 64 + (lane >> 4) * 4;
    const int ocol0 = n0 + wn * 64 + (lane & 15);
#pragma unroll
    for (int i = 0; i < 4; ++i)
#pragma unroll
        for (int j = 0; j < 4; ++j)
#pragma unroll
            for (int r = 0; r < 4; ++r)
                out[(size_t)(orow0 + i * 16 + r) * N + ocol0 + j * 16] = acc[i][j][r];
}

// ---------------------------------------------------------------------------
// Last-resort naive VALU path (no workspace): correct, slow.
// ---------------------------------------------------------------------------
#define MR 16
__global__ __launch_bounds__(256) void naive_kernel(
    const float* __restrict__ x, const int* __restrict__ q,
    const float* __restrict__ sc, float* __restrict__ out,
    int M, int N, int K)
{
    const int n  = blockIdx.x * 256 + threadIdx.x;
    const int m0 = blockIdx.y * MR;
    float acc[MR];
#pragma unroll
    for (int i = 0; i < MR; ++i) acc[i] = 0.f;
    for (int k = 0; k < K; ++k) {
        const float s = sc[(size_t)(k >> 7) * N + n];
        const float w = (float)(q[(size_t)k * N + n] - ZP) * s;
#pragma unroll
        for (int i = 0; i < MR; ++i)
            acc[i] = fmaf(x[(size_t)(m0 + i) * K + k], w, acc[i]);
    }
#pragma unroll
    for (int i = 0; i < MR; ++i)
        out[(size_t)(m0 + i) * N + n] = acc[i];
}

extern "C" void kernel_launch(void* const* d_in, const int* in_sizes, int n_in,
                              void* d_out, int out_size, void* d_ws, size_t ws_size,
                              hipStream_t stream) {
    const float* x  = (const float*)d_in[0];
    const int*   q  = (const int*)d_in[1];
    const float* sc = (const float*)d_in[2];
    float*       o  = (float*)d_out;

    int M = 8192, K = 4096, N = 4096;
    if (!((long long)in_sizes[0] == (long long)M * K &&
          (long long)in_sizes[1] == (long long)K * N &&
          (long long)out_size    == (long long)M * N)) {
        const double S0 = (double)in_sizes[0], S1 = (double)in_sizes[1];
        K = (int)llround(sqrt(S0 * S1 / (double)out_size));
        N = in_sizes[1] / K;
        M = in_sizes[0] / K;
    }

    const size_t xb_bytes = (size_t)M * K * 2;
    const size_t wt_bytes = (size_t)N * K * 2;
    const int ngemm = (M / BM) * (N / BN);

    if (ws_size >= xb_bytes + wt_bytes) {
        ushort* xb = (ushort*)d_ws;
        ushort* wt = (ushort*)((char*)d_ws + xb_bytes);
        conv_x_kernel<<<2048, 256, 0, stream>>>(x, xb, (size_t)M * K / 8);
        dequant_t_kernel<<<dim3(K / 64, N / 64), 256, 0, stream>>>(q, sc, wt, K, N);
        gemm_kernel<false><<<dim3(ngemm), 256, 0, stream>>>(xb, nullptr, wt, o, M, N, K);
    } else if (ws_size >= wt_bytes) {
        ushort* wt = (ushort*)d_ws;
        dequant_t_kernel<<<dim3(K / 64, N / 64), 256, 0, stream>>>(q, sc, wt, K, N);
        gemm_kernel<true><<<dim3(ngemm), 256, 0, stream>>>(nullptr, x, wt, o, M, N, K);
    } else {
        naive_kernel<<<dim3(N / 256, M / MR), 256, 0, stream>>>(x, q, sc, o, M, N, K);
    }
}

// Round 6
// 416.706 us; speedup vs baseline: 1.0830x; 1.0830x over previous
//
#include <hip/hip_runtime.h>
#include <stdint.h>
#include <math.h>

#define GROUP 128
#define ZP 8
#define BM 128
#define BN 128
#define BK 32

typedef short short8 __attribute__((ext_vector_type(8)));   // 8 x bf16 bits
typedef float floatx4 __attribute__((ext_vector_type(4)));

typedef __attribute__((address_space(3))) void lds_void;
typedef const __attribute__((address_space(1))) void gbl_void;
#define GLOAD_LDS16(g, l) \
  __builtin_amdgcn_global_load_lds((gbl_void*)(g), (lds_void*)(l), 16, 0, 0)

#define VMCNT(n) asm volatile("s_waitcnt vmcnt(" #n ")" ::: "memory")
#define LGKM0()  asm volatile("s_waitcnt lgkmcnt(0)" ::: "memory")
#define BAR()    __builtin_amdgcn_s_barrier()
#define SCHEDB() __builtin_amdgcn_sched_barrier(0)

__device__ __forceinline__ ushort f2bf(float f) {  // round-to-nearest-even
    union { float f; uint32_t i; } v; v.f = f;
    uint32_t r = v.i + 0x7FFF + ((v.i >> 16) & 1);
    return (ushort)(r >> 16);
}

// ---------------------------------------------------------------------------
// x fp32 [M*K] -> bf16 [M*K]. Grid-stride, 8 elems/thread/iter.
// ---------------------------------------------------------------------------
__global__ __launch_bounds__(256) void conv_x_kernel(
    const float* __restrict__ x, ushort* __restrict__ xb, size_t total8)
{
    const size_t stride = (size_t)gridDim.x * 256;
    for (size_t id = (size_t)blockIdx.x * 256 + threadIdx.x; id < total8; id += stride) {
        const float4 a = *reinterpret_cast<const float4*>(x + id * 8);
        const float4 b = *reinterpret_cast<const float4*>(x + id * 8 + 4);
        ushort o[8] __attribute__((aligned(16)));
        o[0] = f2bf(a.x); o[1] = f2bf(a.y); o[2] = f2bf(a.z); o[3] = f2bf(a.w);
        o[4] = f2bf(b.x); o[5] = f2bf(b.y); o[6] = f2bf(b.z); o[7] = f2bf(b.w);
        *reinterpret_cast<uint4*>(xb + id * 8) = *reinterpret_cast<const uint4*>(o);
    }
}

// ---------------------------------------------------------------------------
// Dequant + transpose: wt[n][k] = bf16((q[k][n] - 8) * scale_f32[k/128][n])
// ---------------------------------------------------------------------------
__global__ __launch_bounds__(256) void dequant_t_kernel(
    const int* __restrict__ q, const float* __restrict__ scale,
    ushort* __restrict__ wt, int K, int N)
{
    __shared__ ushort T[64 * 68];
    const int t  = threadIdx.x;
    const int k0 = blockIdx.x * 64;
    const int n0 = blockIdx.y * 64;
    const int g  = k0 / GROUP;
    const int c  = (t & 15) * 4;
    const int r0 = (t >> 4);

    const float4 s = *reinterpret_cast<const float4*>(&scale[(size_t)g * N + n0 + c]);

#pragma unroll
    for (int j = 0; j < 4; ++j) {
        const int r = r0 + j * 16;
        const int4 qv = *reinterpret_cast<const int4*>(&q[(size_t)(k0 + r) * N + n0 + c]);
        T[(c + 0) * 68 + r] = f2bf((float)(qv.x - ZP) * s.x);
        T[(c + 1) * 68 + r] = f2bf((float)(qv.y - ZP) * s.y);
        T[(c + 2) * 68 + r] = f2bf((float)(qv.z - ZP) * s.z);
        T[(c + 3) * 68 + r] = f2bf((float)(qv.w - ZP) * s.w);
    }
    __syncthreads();
#pragma unroll
    for (int j = 0; j < 4; ++j) {
        const int nn = r0 + j * 16;
        const int kk = c;
        const uint2 v = *reinterpret_cast<const uint2*>(&T[nn * 68 + kk]);
        *reinterpret_cast<uint2*>(&wt[(size_t)(n0 + nn) * K + k0 + kk]) = v;
    }
}

// ---------------------------------------------------------------------------
// GEMM: A bf16 [M][K] x Wt bf16 [N][K] -> out fp32 [M][N]
// 128x128 tile, BK=32, 4 waves (2x2), 4x4 16x16x32 bf16 fragments per wave.
// 4-deep LDS ring, counted vmcnt (T4), raw barriers, XOR-swizzled LDS (T2).
// Pipeline: tile T+3 staged during tile T. vmcnt(8) at tile boundary
// guarantees (in-order retirement) the next tile's 4 loads have landed.
// ---------------------------------------------------------------------------
__global__ __launch_bounds__(256, 2) void gemm_ring_kernel(
    const ushort* __restrict__ Ab, const ushort* __restrict__ Wt,
    float* __restrict__ out, int M, int N, int K)
{
    __shared__ ushort As[4 * 4096];   // 4 bufs x 8KB (128 rows x 64B)
    __shared__ ushort Bs[4 * 4096];

    const int bid = blockIdx.x;
    const int nwg = gridDim.x;
    int wg = bid;
    if ((nwg & 7) == 0) {             // bijective XCD swizzle
        const int cpx = nwg >> 3;
        wg = (bid & 7) * cpx + (bid >> 3);
    }
    const int ntn = N / BN;
    const int m0 = (wg / ntn) * BM;
    const int n0 = (wg % ntn) * BN;

    const int t    = threadIdx.x;
    const int lane = t & 63;
    const int wm   = (t >> 6) >> 1;
    const int wn   = (t >> 6) & 1;
    const int NT   = K / BK;

    // Staging: thread t stages 16B chunks. Linear LDS dest byte f = i*4096+t*16
    // -> row r = f/64, col-byte c' = f%64. Swizzle: LDS[r][c'] holds global
    // k-chunk (c'/16) ^ ((r>>1)&3)  (pre-swizzled source, linear dest).
    const ushort* pa[2]; const ushort* pb[2];
    int dst[2];
#pragma unroll
    for (int i = 0; i < 2; ++i) {
        const int r = i * 64 + (t >> 2);
        const int j = (t & 3) ^ ((r >> 1) & 3);
        pa[i] = Ab + (size_t)(m0 + r) * K + j * 8;
        pb[i] = Wt + (size_t)(n0 + r) * K + j * 8;
        dst[i] = i * 4096 + t * 16;
    }

    // Fragment read offsets (bytes within one 8KB buffer), swizzled read.
    const int e16 = (lane >> 4) * 16;              // k-chunk byte
    const int sw  = (((lane & 15) >> 1) & 3) << 4; // row-dependent XOR
    int aoff[4], boff[4];
#pragma unroll
    for (int i = 0; i < 4; ++i) {
        aoff[i] = (wm * 64 + i * 16 + (lane & 15)) * 64 + (e16 ^ sw);
        boff[i] = (wn * 64 + i * 16 + (lane & 15)) * 64 + (e16 ^ sw);
    }

    floatx4 acc[4][4];
#pragma unroll
    for (int i = 0; i < 4; ++i)
#pragma unroll
        for (int j = 0; j < 4; ++j) acc[i][j] = floatx4{0.f, 0.f, 0.f, 0.f};

    // Prologue: stage tiles 0,1,2 into bufs 0,1,2 (issue order = tile order).
#pragma unroll
    for (int U = 0; U < 3; ++U) {
        GLOAD_LDS16(pa[0] + U * 32, (char*)As + U * 8192 + dst[0]);
        GLOAD_LDS16(pa[1] + U * 32, (char*)As + U * 8192 + dst[1]);
        GLOAD_LDS16(pb[0] + U * 32, (char*)Bs + U * 8192 + dst[0]);
        GLOAD_LDS16(pb[1] + U * 32, (char*)Bs + U * 8192 + dst[1]);
    }
    VMCNT(8);                          // tile 0's 4 loads retired
    BAR();

    auto body = [&](int T, bool issue) __attribute__((always_inline)) {
        if (issue) {                   // stage tile T+3 into buf (T+3)&3
            const int bD = (T + 3) & 3;
            const int ko = (T + 3) * 32;
            GLOAD_LDS16(pa[0] + ko, (char*)As + bD * 8192 + dst[0]);
            GLOAD_LDS16(pa[1] + ko, (char*)As + bD * 8192 + dst[1]);
            GLOAD_LDS16(pb[0] + ko, (char*)Bs + bD * 8192 + dst[0]);
            GLOAD_LDS16(pb[1] + ko, (char*)Bs + bD * 8192 + dst[1]);
        }
        const char* Ab_ = (const char*)As + (T & 3) * 8192;
        const char* Bb_ = (const char*)Bs + (T & 3) * 8192;
        short8 af[4], bf[4];
#pragma unroll
        for (int i = 0; i < 4; ++i) {
            af[i] = *reinterpret_cast<const short8*>(Ab_ + aoff[i]);
            bf[i] = *reinterpret_cast<const short8*>(Bb_ + boff[i]);
        }
#pragma unroll
        for (int i = 0; i < 4; ++i)
#pragma unroll
            for (int j = 0; j < 4; ++j)
                acc[i][j] = __builtin_amdgcn_mfma_f32_16x16x32_bf16(af[i], bf[j], acc[i][j], 0, 0, 0);
        LGKM0();                       // drain this wave's ds_reads
        SCHEDB();                      // ...and pin them before the barrier
    };

    for (int T = 0; T + 3 < NT; ++T) { // T = 0 .. NT-4, always issues
        body(T, true);
        VMCNT(8);                      // oldest 4 (= tile T+1) retired
        BAR();
    }
    body(NT - 3, false); VMCNT(4); BAR();
    body(NT - 2, false); VMCNT(0); BAR();
    body(NT - 1, false);

    // Epilogue: D col = lane&15, row = 4*(lane>>4)+reg  (fp32 out)
    const int orow0 = m0 + wm * 64 + (lane >> 4) * 4;
    const int ocol0 = n0 + wn * 64 + (lane & 15);
#pragma unroll
    for (int i = 0; i < 4; ++i)
#pragma unroll
        for (int j = 0; j < 4; ++j)
#pragma unroll
            for (int r = 0; r < 4; ++r)
                out[(size_t)(orow0 + i * 16 + r) * N + ocol0 + j * 16] = acc[i][j][r];
}

// ---------------------------------------------------------------------------
// Last-resort naive VALU path (no workspace): correct, slow.
// ---------------------------------------------------------------------------
#define MR 16
__global__ __launch_bounds__(256) void naive_kernel(
    const float* __restrict__ x, const int* __restrict__ q,
    const float* __restrict__ sc, float* __restrict__ out,
    int M, int N, int K)
{
    const int n  = blockIdx.x * 256 + threadIdx.x;
    const int m0 = blockIdx.y * MR;
    float acc[MR];
#pragma unroll
    for (int i = 0; i < MR; ++i) acc[i] = 0.f;
    for (int k = 0; k < K; ++k) {
        const float s = sc[(size_t)(k / GROUP) * N + n];
        const float w = (float)(q[(size_t)k * N + n] - ZP) * s;
#pragma unroll
        for (int i = 0; i < MR; ++i)
            acc[i] = fmaf(x[(size_t)(m0 + i) * K + k], w, acc[i]);
    }
#pragma unroll
    for (int i = 0; i < MR; ++i)
        out[(size_t)(m0 + i) * N + n] = acc[i];
}

extern "C" void kernel_launch(void* const* d_in, const int* in_sizes, int n_in,
                              void* d_out, int out_size, void* d_ws, size_t ws_size,
                              hipStream_t stream) {
    const float* x  = (const float*)d_in[0];
    const int*   q  = (const int*)d_in[1];
    const float* sc = (const float*)d_in[2];
    float*       o  = (float*)d_out;

    int M = 8192, K = 4096, N = 4096;
    if (!((long long)in_sizes[0] == (long long)M * K &&
          (long long)in_sizes[1] == (long long)K * N &&
          (long long)out_size    == (long long)M * N)) {
        const double S0 = (double)in_sizes[0], S1 = (double)in_sizes[1];
        K = (int)llround(sqrt(S0 * S1 / (double)out_size));
        N = in_sizes[1] / K;
        M = in_sizes[0] / K;
    }

    const size_t xb_bytes = (size_t)M * K * 2;
    const size_t wt_bytes = (size_t)N * K * 2;

    const bool ok = (M % BM == 0) && (N % BN == 0) && (K % BK == 0) &&
                    (K / BK >= 4) && (N % 64 == 0) && (K % 64 == 0) &&
                    (K % GROUP == 0) && (ws_size >= xb_bytes + wt_bytes);

    if (ok) {
        ushort* xb = (ushort*)d_ws;
        ushort* wt = (ushort*)((char*)d_ws + xb_bytes);
        conv_x_kernel<<<2048, 256, 0, stream>>>(x, xb, (size_t)M * K / 8);
        dequant_t_kernel<<<dim3(K / 64, N / 64), 256, 0, stream>>>(q, sc, wt, K, N);
        const int ngemm = (M / BM) * (N / BN);
        gemm_ring_kernel<<<dim3(ngemm), 256, 0, stream>>>(xb, wt, o, M, N, K);
    } else {
        naive_kernel<<<dim3(N / 256, M / MR), 256, 0, stream>>>(x, q, sc, o, M, N, K);
    }
}

// Round 7
// 294.789 us; speedup vs baseline: 1.5309x; 1.4136x over previous
//
#include <hip/hip_runtime.h>
#include <stdint.h>
#include <math.h>

#define GROUP 128
#define ZP 8
#define BM 256
#define BN 256
#define BK 32

typedef short short8 __attribute__((ext_vector_type(8)));   // 8 x bf16 bits
typedef float floatx4 __attribute__((ext_vector_type(4)));

typedef __attribute__((address_space(3))) void lds_void;
typedef const __attribute__((address_space(1))) void gbl_void;
#define GLOAD_LDS16(g, l) \
  __builtin_amdgcn_global_load_lds((gbl_void*)(g), (lds_void*)(l), 16, 0, 0)

#define VMCNT(n) asm volatile("s_waitcnt vmcnt(" #n ")" ::: "memory")
#define LGKM0()  asm volatile("s_waitcnt lgkmcnt(0)" ::: "memory")
#define BAR()    __builtin_amdgcn_s_barrier()
#define SCHEDB() __builtin_amdgcn_sched_barrier(0)

__device__ __forceinline__ ushort f2bf(float f) {  // round-to-nearest-even
    union { float f; uint32_t i; } v; v.f = f;
    uint32_t r = v.i + 0x7FFF + ((v.i >> 16) & 1);
    return (ushort)(r >> 16);
}

// ---------------------------------------------------------------------------
// x fp32 [M*K] -> bf16 [M*K]. Grid-stride, 8 elems/thread/iter.
// ---------------------------------------------------------------------------
__global__ __launch_bounds__(256) void conv_x_kernel(
    const float* __restrict__ x, ushort* __restrict__ xb, size_t total8)
{
    const size_t stride = (size_t)gridDim.x * 256;
    for (size_t id = (size_t)blockIdx.x * 256 + threadIdx.x; id < total8; id += stride) {
        const float4 a = *reinterpret_cast<const float4*>(x + id * 8);
        const float4 b = *reinterpret_cast<const float4*>(x + id * 8 + 4);
        ushort o[8] __attribute__((aligned(16)));
        o[0] = f2bf(a.x); o[1] = f2bf(a.y); o[2] = f2bf(a.z); o[3] = f2bf(a.w);
        o[4] = f2bf(b.x); o[5] = f2bf(b.y); o[6] = f2bf(b.z); o[7] = f2bf(b.w);
        *reinterpret_cast<uint4*>(xb + id * 8) = *reinterpret_cast<const uint4*>(o);
    }
}

// ---------------------------------------------------------------------------
// Dequant + transpose: wt[n][k] = bf16((q[k][n] - 8) * scale_f32[k/128][n])
// ---------------------------------------------------------------------------
__global__ __launch_bounds__(256) void dequant_t_kernel(
    const int* __restrict__ q, const float* __restrict__ scale,
    ushort* __restrict__ wt, int K, int N)
{
    __shared__ ushort T[64 * 68];
    const int t  = threadIdx.x;
    const int k0 = blockIdx.x * 64;
    const int n0 = blockIdx.y * 64;
    const int g  = k0 / GROUP;
    const int c  = (t & 15) * 4;
    const int r0 = (t >> 4);

    const float4 s = *reinterpret_cast<const float4*>(&scale[(size_t)g * N + n0 + c]);

#pragma unroll
    for (int j = 0; j < 4; ++j) {
        const int r = r0 + j * 16;
        const int4 qv = *reinterpret_cast<const int4*>(&q[(size_t)(k0 + r) * N + n0 + c]);
        T[(c + 0) * 68 + r] = f2bf((float)(qv.x - ZP) * s.x);
        T[(c + 1) * 68 + r] = f2bf((float)(qv.y - ZP) * s.y);
        T[(c + 2) * 68 + r] = f2bf((float)(qv.z - ZP) * s.z);
        T[(c + 3) * 68 + r] = f2bf((float)(qv.w - ZP) * s.w);
    }
    __syncthreads();
#pragma unroll
    for (int j = 0; j < 4; ++j) {
        const int nn = r0 + j * 16;
        const int kk = c;
        const uint2 v = *reinterpret_cast<const uint2*>(&T[nn * 68 + kk]);
        *reinterpret_cast<uint2*>(&wt[(size_t)(n0 + nn) * K + k0 + kk]) = v;
    }
}

// ---------------------------------------------------------------------------
// GEMM: A bf16 [M][K] x Wt bf16 [N][K] -> out fp32 [M][N]
// 256x256 tile, BK=32, 8 waves (2Mx4N), per-wave 128x64 (acc 8x4 frags).
// 4-slot LDS ring (slot = 32KB: A[256][32] + B[256][32]), 128 KiB total.
// Sync skeleton identical to the round-6-validated ring: stage tile T+3
// during window T; vmcnt(8) + barrier per window; tail vmcnt(4)/vmcnt(0).
// XOR chunk swizzle applied source-side (stage) and read-side (identical
// involution): LDS[r][chunk c] holds global k-chunk c ^ ((r>>1)&3).
// ---------------------------------------------------------------------------
__global__ __launch_bounds__(512, 2) void gemm256_ring_kernel(
    const ushort* __restrict__ Ab, const ushort* __restrict__ Wt,
    float* __restrict__ out, int M, int N, int K)
{
    __shared__ ushort smem[4 * 16384];   // 4 slots x 32 KiB = 128 KiB

    const int bid = blockIdx.x;
    const int nwg = gridDim.x;
    int wg = bid;
    if ((nwg & 7) == 0) {                // bijective XCD swizzle
        const int cpx = nwg >> 3;
        wg = (bid & 7) * cpx + (bid >> 3);
    }
    const int ntn = N / BN;
    const int m0 = (wg / ntn) * BM;
    const int n0 = (wg % ntn) * BN;

    const int t    = threadIdx.x;
    const int lane = t & 63;
    const int w    = t >> 6;
    const int wm   = w >> 2;             // 2 (M) x 4 (N) wave grid
    const int wn   = w & 3;
    const int NT   = K / BK;

    // Staging: statement s covers rows s*128 + (t>>2); thread t stages the
    // 16B chunk j = (t&3) ^ ((row>>1)&3) of the row's 64B (pre-swizzled
    // global source, linear LDS destination).
    const ushort* pa[2]; const ushort* pb[2];
    int dstA[2], dstB[2];
#pragma unroll
    for (int s = 0; s < 2; ++s) {
        const int r = s * 128 + (t >> 2);
        const int j = (t & 3) ^ ((r >> 1) & 3);
        pa[s] = Ab + (size_t)(m0 + r) * K + j * 8;
        pb[s] = Wt + (size_t)(n0 + r) * K + j * 8;
        dstA[s] = s * 8192 + t * 16;            // byte offsets within slot
        dstB[s] = 16384 + s * 8192 + t * 16;
    }

    // Fragment read byte-offsets within a slot (swizzled read).
    int aoff[8], boff[4];
#pragma unroll
    for (int i = 0; i < 8; ++i) {
        const int r = wm * 128 + i * 16 + (lane & 15);
        aoff[i] = r * 64 + (((lane >> 4) ^ ((r >> 1) & 3)) << 4);
    }
#pragma unroll
    for (int j = 0; j < 4; ++j) {
        const int r = wn * 64 + j * 16 + (lane & 15);
        boff[j] = 16384 + r * 64 + (((lane >> 4) ^ ((r >> 1) & 3)) << 4);
    }

    floatx4 acc[8][4];
#pragma unroll
    for (int i = 0; i < 8; ++i)
#pragma unroll
        for (int j = 0; j < 4; ++j) acc[i][j] = floatx4{0.f, 0.f, 0.f, 0.f};

    // Prologue: stage tiles 0,1,2 into slots 0,1,2 (issue order = tile order).
#pragma unroll
    for (int U = 0; U < 3; ++U) {
        char* sb = (char*)smem + U * 32768;
        GLOAD_LDS16(pa[0] + U * 32, sb + dstA[0]);
        GLOAD_LDS16(pa[1] + U * 32, sb + dstA[1]);
        GLOAD_LDS16(pb[0] + U * 32, sb + dstB[0]);
        GLOAD_LDS16(pb[1] + U * 32, sb + dstB[1]);
    }
    VMCNT(8);                            // tile 0's 4 statements retired
    BAR();

    auto body = [&](int T, bool issue) __attribute__((always_inline)) {
        if (issue) {                     // stage tile T+3 into slot (T+3)&3
            char* sb = (char*)smem + ((T + 3) & 3) * 32768;
            const int ko = (T + 3) * 32;
            GLOAD_LDS16(pa[0] + ko, sb + dstA[0]);
            GLOAD_LDS16(pa[1] + ko, sb + dstA[1]);
            GLOAD_LDS16(pb[0] + ko, sb + dstB[0]);
            GLOAD_LDS16(pb[1] + ko, sb + dstB[1]);
        }
        const char* sb = (const char*)smem + (T & 3) * 32768;
        short8 af[8], bf[4];
#pragma unroll
        for (int i = 0; i < 8; ++i)
            af[i] = *reinterpret_cast<const short8*>(sb + aoff[i]);
#pragma unroll
        for (int j = 0; j < 4; ++j)
            bf[j] = *reinterpret_cast<const short8*>(sb + boff[j]);
        __builtin_amdgcn_s_setprio(1);
#pragma unroll
        for (int i = 0; i < 8; ++i)
#pragma unroll
            for (int j = 0; j < 4; ++j)
                acc[i][j] = __builtin_amdgcn_mfma_f32_16x16x32_bf16(af[i], bf[j], acc[i][j], 0, 0, 0);
        __builtin_amdgcn_s_setprio(0);
        LGKM0();                         // this wave's ds_reads drained...
        SCHEDB();                        // ...and pinned before the barrier
    };

    for (int T = 0; T + 3 < NT; ++T) {   // always issues (tile T+3)
        body(T, true);
        VMCNT(8);                        // oldest 4 (= tile T+1's stmts) retired
        BAR();
    }
    body(NT - 3, false); VMCNT(4); BAR();
    body(NT - 2, false); VMCNT(0); BAR();
    body(NT - 1, false);

    // Epilogue: D col = lane&15, row = 4*(lane>>4)+reg  (fp32 out)
    const int orow0 = m0 + wm * 128 + (lane >> 4) * 4;
    const int ocol0 = n0 + wn * 64 + (lane & 15);
#pragma unroll
    for (int i = 0; i < 8; ++i)
#pragma unroll
        for (int j = 0; j < 4; ++j)
#pragma unroll
            for (int r = 0; r < 4; ++r)
                out[(size_t)(orow0 + i * 16 + r) * N + ocol0 + j * 16] = acc[i][j][r];
}

// ---------------------------------------------------------------------------
// Last-resort naive VALU path (no workspace / odd shapes): correct, slow.
// ---------------------------------------------------------------------------
#define MR 16
__global__ __launch_bounds__(256) void naive_kernel(
    const float* __restrict__ x, const int* __restrict__ q,
    const float* __restrict__ sc, float* __restrict__ out,
    int M, int N, int K)
{
    const int n  = blockIdx.x * 256 + threadIdx.x;
    const int m0 = blockIdx.y * MR;
    float acc[MR];
#pragma unroll
    for (int i = 0; i < MR; ++i) acc[i] = 0.f;
    for (int k = 0; k < K; ++k) {
        const float s = sc[(size_t)(k / GROUP) * N + n];
        const float w = (float)(q[(size_t)k * N + n] - ZP) * s;
#pragma unroll
        for (int i = 0; i < MR; ++i)
            acc[i] = fmaf(x[(size_t)(m0 + i) * K + k], w, acc[i]);
    }
#pragma unroll
    for (int i = 0; i < MR; ++i)
        out[(size_t)(m0 + i) * N + n] = acc[i];
}

extern "C" void kernel_launch(void* const* d_in, const int* in_sizes, int n_in,
                              void* d_out, int out_size, void* d_ws, size_t ws_size,
                              hipStream_t stream) {
    const float* x  = (const float*)d_in[0];
    const int*   q  = (const int*)d_in[1];
    const float* sc = (const float*)d_in[2];
    float*       o  = (float*)d_out;

    int M = 8192, K = 4096, N = 4096;
    if (!((long long)in_sizes[0] == (long long)M * K &&
          (long long)in_sizes[1] == (long long)K * N &&
          (long long)out_size    == (long long)M * N)) {
        const double S0 = (double)in_sizes[0], S1 = (double)in_sizes[1];
        K = (int)llround(sqrt(S0 * S1 / (double)out_size));
        N = in_sizes[1] / K;
        M = in_sizes[0] / K;
    }

    const size_t xb_bytes = (size_t)M * K * 2;
    const size_t wt_bytes = (size_t)N * K * 2;

    const bool ok = (M % BM == 0) && (N % BN == 0) && (K % BK == 0) &&
                    (K / BK >= 4) && (N % 64 == 0) && (K % 64 == 0) &&
                    (K % GROUP == 0) && (ws_size >= xb_bytes + wt_bytes);

    if (ok) {
        ushort* xb = (ushort*)d_ws;
        ushort* wt = (ushort*)((char*)d_ws + xb_bytes);
        conv_x_kernel<<<2048, 256, 0, stream>>>(x, xb, (size_t)M * K / 8);
        dequant_t_kernel<<<dim3(K / 64, N / 64), 256, 0, stream>>>(q, sc, wt, K, N);
        const int ngemm = (M / BM) * (N / BN);
        gemm256_ring_kernel<<<dim3(ngemm), 512, 0, stream>>>(xb, wt, o, M, N, K);
    } else {
        naive_kernel<<<dim3(N / 256, M / MR), 256, 0, stream>>>(x, q, sc, o, M, N, K);
    }
}